// Round 12
// baseline (153.258 us; speedup 1.0000x reference)
//
#include <hip/hip_runtime.h>
#include <cmath>

typedef __attribute__((ext_vector_type(8))) short short8;
typedef __attribute__((ext_vector_type(4))) float f32x4;

static __device__ __forceinline__ unsigned cvtpk(float lo, float hi) {
    unsigned r;
    asm("v_cvt_pk_bf16_f32 %0, %1, %2" : "=v"(r) : "v"(lo), "v"(hi));
    return r;
}
// 3-level RNE split of a pair of floats -> 3 packed-bf16 dwords; v = s1+s2+s3 + O(2^-27 |v|)
static __device__ __forceinline__ void split3pk(float v0, float v1,
                                                unsigned& o1, unsigned& o2, unsigned& o3) {
    o1 = cvtpk(v0, v1);
    float r0 = v0 - __uint_as_float(o1 << 16);
    float r1 = v1 - __uint_as_float(o1 & 0xffff0000u);
    o2 = cvtpk(r0, r1);
    float q0 = r0 - __uint_as_float(o2 << 16);
    float q1 = r1 - __uint_as_float(o2 & 0xffff0000u);
    o3 = cvtpk(q0, q1);
}

union FragU { short8 s; unsigned u[4]; };

#define PH 1048576   // h plane elems (16384*64)
#define PB 131072    // emb/W plane elems (2048*64)

// ---------------- prep: zero wacc + inv-norms + excitability bonus ----------
// global order: [qk 0..511][fv 512..767][q 768..1279][k(rel) 1280..1791][val 1792..2047]
__global__ void prep_kernel(const float* __restrict__ emb,
                            const float* __restrict__ emb_rel_k,
                            const float* __restrict__ ema_qk,
                            const float* __restrict__ ema_v,
                            const float* __restrict__ ema_rel,
                            const float* __restrict__ ema_val,
                            float* __restrict__ invn,
                            float* __restrict__ bonus,
                            float* __restrict__ wacc)
{
    int n = blockIdx.x * 64 + threadIdx.x;   // 32 x 64 -> 2048
    {
        float4 z = {0.f, 0.f, 0.f, 0.f};
        *(float4*)(wacc + (size_t)n * 8)     = z;
        *(float4*)(wacc + (size_t)n * 8 + 4) = z;
    }
    const float* row;
    float ema;
    if (n < 512)       { row = emb + (size_t)n * 64;                ema = ema_qk[n]; }
    else if (n < 768)  { row = emb + (size_t)n * 64;                ema = ema_v[n - 512]; }
    else if (n < 1280) { row = emb + (size_t)n * 64;                ema = ema_rel[n - 768]; }
    else if (n < 1792) { row = emb_rel_k + (size_t)(n - 1280) * 64; ema = ema_rel[n - 1280]; }
    else               { row = emb + (size_t)(n - 512) * 64;        ema = ema_val[n - 1792]; }
    float s = 0.f;
    #pragma unroll
    for (int k = 0; k < 64; k += 4) {
        float4 v = *(const float4*)(row + k);
        s += v.x*v.x + v.y*v.y + v.z*v.z + v.w*v.w;
    }
    invn[n] = 1.0f / sqrtf(s);
    float ex = 1.0f - ema * (1.0f / 1.5f);   // TAU = 1.5
    ex = fminf(fmaxf(ex, 0.f), 1.f);
    bonus[n] = ex * 1.0f;                    // EXC_W = 1.0
}

// ---------------- pack W into 3 bf16 split planes, MFMA B-fragment order ----
// plane: [ksg 0..63][t 0..3][lane 0..63][j 0..7]; col=16t+(l&15), k=ksg*32+(l>>4)*8+j
__global__ void wtpack3_kernel(const float* __restrict__ proj_w, unsigned short* __restrict__ wp)
{
    int idx = blockIdx.x * 256 + threadIdx.x;   // 16384
    int l = idx & 63;
    int t = (idx >> 6) & 3;
    int ksg = idx >> 8;
    int col = t * 16 + (l & 15);
    int kb = ksg * 32 + (l >> 4) * 8;
    float4 w0 = *(const float4*)(proj_w + (size_t)col * 2048 + kb);
    float4 w1 = *(const float4*)(proj_w + (size_t)col * 2048 + kb + 4);
    float v[8] = {w0.x, w0.y, w0.z, w0.w, w1.x, w1.y, w1.z, w1.w};
    FragU s1, s2, s3;
    #pragma unroll
    for (int p = 0; p < 4; ++p)
        split3pk(v[2*p], v[2*p+1], s1.u[p], s2.u[p], s3.u[p]);
    size_t base = (size_t)ksg * 2048 + t * 512 + l * 8;
    *(short8*)(wp + base)          = s1.s;
    *(short8*)(wp + PB + base)     = s2.s;
    *(short8*)(wp + 2 * PB + base) = s3.s;
}

// ---------------- pack emb (global order) into 3 bf16 B-frag planes ---------
// plane: [nt 0..127][ks 0..1][lane][j]; neuron=nt*16+(l&15), k=ks*32+(l>>4)*8+j
__global__ void embpack_kernel(const float* __restrict__ emb,
                               const float* __restrict__ emb_rel_k,
                               unsigned short* __restrict__ bp)
{
    int idx = blockIdx.x * 256 + threadIdx.x;   // 16384
    int l = idx & 63;
    int ks = (idx >> 6) & 1;
    int nt = idx >> 7;
    int n = nt * 16 + (l & 15);
    const float* src;
    if (n < 1280)      src = emb + (size_t)n * 64;
    else if (n < 1792) src = emb_rel_k + (size_t)(n - 1280) * 64;
    else               src = emb + (size_t)(n - 512) * 64;
    int c0 = ks * 32 + (l >> 4) * 8;
    float4 w0 = *(const float4*)(src + c0);
    float4 w1 = *(const float4*)(src + c0 + 4);
    float v[8] = {w0.x, w0.y, w0.z, w0.w, w1.x, w1.y, w1.z, w1.w};
    FragU s1, s2, s3;
    #pragma unroll
    for (int p = 0; p < 4; ++p)
        split3pk(v[2*p], v[2*p+1], s1.u[p], s2.u[p], s3.u[p]);
    size_t base = ((size_t)nt * 2 + ks) * 512 + l * 8;
    *(short8*)(bp + base)          = s1.s;
    *(short8*)(bp + PB + base)     = s2.s;
    *(short8*)(bp + 2 * PB + base) = s3.s;
}

#define MFMA16(a, b, c) __builtin_amdgcn_mfma_f32_16x16x32_bf16(a, b, c, 0, 0, 0)

// ---------------- proj GEMM v3: shared 12KB slab, 4 blocks/CU ---------------
// grid (256 rowgroups, 4 kp); block = 4 waves, 64 rows, K-slice 512.
// Per k-step: block stages ONE 12 KB slab (3 planes x 2048 shorts) that ALL
// 4 waves consume (4x LDS reuse); double-buffered, one barrier per step.
// Epilogue: coalesced f32 partial store to hpart[kp] (no in-block reduce).
__launch_bounds__(256, 4)
__global__ void proj_kernel(const float* __restrict__ x,
                            const unsigned short* __restrict__ wp,
                            float* __restrict__ hpart)
{
    __shared__ short sBuf[2][6144];   // 2 x 12 KB

    const int tid = threadIdx.x;
    const int wave = tid >> 6, lane = tid & 63;
    const int g_ = lane >> 4, r_ = lane & 15;
    const int kp = blockIdx.y;
    const int row0 = blockIdx.x * 64 + wave * 16;

    const float* xa = x + (size_t)(row0 + r_) * 2048 + kp * 512 + g_ * 8;

    f32x4 acc[4];
    #pragma unroll
    for (int t = 0; t < 4; ++t) acc[t] = (f32x4){0.f, 0.f, 0.f, 0.f};

    // prologue: stage slab for ksg0 into buf 0 (3 x float4 per thread, linear)
    {
        const size_t ks0 = (size_t)(kp * 16) * 2048 + tid * 8;
        float4 v0 = *(const float4*)(wp + ks0);
        float4 v1 = *(const float4*)(wp + PB + ks0);
        float4 v2 = *(const float4*)(wp + 2 * PB + ks0);
        *(float4*)(&sBuf[0][tid * 8])        = v0;
        *(float4*)(&sBuf[0][2048 + tid * 8]) = v1;
        *(float4*)(&sBuf[0][4096 + tid * 8]) = v2;
    }
    __syncthreads();

    float4 a0 = *(const float4*)(xa);
    float4 a1 = *(const float4*)(xa + 4);
    int cur = 0;

    for (int ks = 0; ks < 16; ++ks) {
        // issue next-slab staging loads early
        float4 v0, v1, v2;
        if (ks < 15) {
            const size_t nb = (size_t)(kp * 16 + ks + 1) * 2048 + tid * 8;
            v0 = *(const float4*)(wp + nb);
            v1 = *(const float4*)(wp + PB + nb);
            v2 = *(const float4*)(wp + 2 * PB + nb);
        }
        // A prefetch for next k-step
        float4 na0, na1;
        if (ks < 15) {
            na0 = *(const float4*)(xa + (ks + 1) * 32);
            na1 = *(const float4*)(xa + (ks + 1) * 32 + 4);
        }
        // B frags from the shared slab
        short8 B1[4], B2[4], B3[4];
        #pragma unroll
        for (int t = 0; t < 4; ++t) {
            B1[t] = *(const short8*)(&sBuf[cur][t * 512 + lane * 8]);
            B2[t] = *(const short8*)(&sBuf[cur][2048 + t * 512 + lane * 8]);
            B3[t] = *(const short8*)(&sBuf[cur][4096 + t * 512 + lane * 8]);
        }
        // split A (RNE x3 via cvt_pk)
        float av[8] = {a0.x, a0.y, a0.z, a0.w, a1.x, a1.y, a1.z, a1.w};
        FragU A1, A2, A3;
        #pragma unroll
        for (int p = 0; p < 4; ++p)
            split3pk(av[2*p], av[2*p+1], A1.u[p], A2.u[p], A3.u[p]);
        #pragma unroll
        for (int t = 0; t < 4; ++t) {
            acc[t] = MFMA16(A1.s, B1[t], acc[t]);
            acc[t] = MFMA16(A1.s, B2[t], acc[t]);
            acc[t] = MFMA16(A2.s, B1[t], acc[t]);
            acc[t] = MFMA16(A2.s, B2[t], acc[t]);
            acc[t] = MFMA16(A1.s, B3[t], acc[t]);
            acc[t] = MFMA16(A3.s, B1[t], acc[t]);
        }
        // land staged regs; one barrier per k-step
        if (ks < 15) {
            *(float4*)(&sBuf[cur ^ 1][tid * 8])        = v0;
            *(float4*)(&sBuf[cur ^ 1][2048 + tid * 8]) = v1;
            *(float4*)(&sBuf[cur ^ 1][4096 + tid * 8]) = v2;
            __syncthreads();
            cur ^= 1;
        }
        a0 = na0; a1 = na1;
    }

    // coalesced partial store: row = g_*4+rr, col = t*16+r_
    float* hp = hpart + (size_t)kp * PH + (size_t)row0 * 64;
    #pragma unroll
    for (int t = 0; t < 4; ++t)
        #pragma unroll
        for (int rr = 0; rr < 4; ++rr)
            hp[(g_ * 4 + rr) * 64 + t * 16 + r_] = acc[t][rr];
}

// ---------------- hsum + pack: h = sum 4 partials + bias -> 3 A-frag planes -
// thread -> (rg 0..1023, ks 0..1, lane 0..63): row=rg*16+(l&15), c0=ks*32+(l>>4)*8
__global__ void hsumpack_kernel(const float* __restrict__ hpart,
                                const float* __restrict__ proj_b,
                                unsigned short* __restrict__ hs)
{
    int idx = blockIdx.x * 256 + threadIdx.x;   // 131072
    int lane = idx & 63;
    int ks = (idx >> 6) & 1;
    int rg = idx >> 7;
    int row = rg * 16 + (lane & 15);
    int c0 = ks * 32 + (lane >> 4) * 8;
    size_t o = (size_t)row * 64 + c0;

    float4 s0 = *(const float4*)(hpart + o);
    float4 s1 = *(const float4*)(hpart + o + 4);
    #pragma unroll
    for (int p = 1; p < 4; ++p) {
        float4 u0 = *(const float4*)(hpart + (size_t)p * PH + o);
        float4 u1 = *(const float4*)(hpart + (size_t)p * PH + o + 4);
        s0.x += u0.x; s0.y += u0.y; s0.z += u0.z; s0.w += u0.w;
        s1.x += u1.x; s1.y += u1.y; s1.z += u1.z; s1.w += u1.w;
    }
    float4 b0 = *(const float4*)(proj_b + c0);
    float4 b1 = *(const float4*)(proj_b + c0 + 4);
    s0.x += b0.x; s0.y += b0.y; s0.z += b0.z; s0.w += b0.w;
    s1.x += b1.x; s1.y += b1.y; s1.z += b1.z; s1.w += b1.w;

    float hv[8] = {s0.x, s0.y, s0.z, s0.w, s1.x, s1.y, s1.z, s1.w};
    FragU t1, t2, t3;
    #pragma unroll
    for (int p = 0; p < 4; ++p)
        split3pk(hv[2*p], hv[2*p+1], t1.u[p], t2.u[p], t3.u[p]);
    size_t base = ((size_t)rg * 2 + ks) * 512 + lane * 8;
    *(short8*)(hs + base)          = t1.s;
    *(short8*)(hs + PH + base)     = t2.s;
    *(short8*)(hs + 2 * PH + base) = t3.s;
}

// ---------------- routing via MFMA (round-8 form: best measured) ------------
// Block: 16 rows, 8 waves (512 thr); wave w owns neurons [w*256, w*256+256).
// Segments align to waves: 0-1=qk, 2=fv, 3-4=q, 5-6=k, 7=val.
__launch_bounds__(512, 4)
__global__ void route_kernel(const unsigned short* __restrict__ hs,
                             const unsigned short* __restrict__ bp,
                             const float* __restrict__ imp,
                             const float* __restrict__ invn_g,
                             const float* __restrict__ bonus_g,
                             float* __restrict__ wout)
{
    __shared__ float2 red[16][8];

    const int tid = threadIdx.x;
    const int wave = tid >> 6, lane = tid & 63;
    const int g_ = lane >> 4, r_ = lane & 15;
    const int rowBase = blockIdx.x * 16;
    const int b = rowBase >> 11;
    const int n0 = wave * 256;

    short8 A1[2], A2[2], A3[2];
    #pragma unroll
    for (int ks = 0; ks < 2; ++ks) {
        size_t base = ((size_t)blockIdx.x * 2 + ks) * 512 + lane * 8;
        A1[ks] = *(const short8*)(hs + base);
        A2[ks] = *(const short8*)(hs + PH + base);
        A3[ks] = *(const short8*)(hs + 2 * PH + base);
    }

    f32x4 acc[16];
    #pragma unroll
    for (int t = 0; t < 16; ++t) acc[t] = (f32x4){0.f, 0.f, 0.f, 0.f};

    #pragma unroll
    for (int t = 0; t < 16; ++t) {
        const int nt = wave * 16 + t;
        #pragma unroll
        for (int ks = 0; ks < 2; ++ks) {
            size_t base = ((size_t)nt * 2 + ks) * 512 + lane * 8;
            short8 B1 = *(const short8*)(bp + base);
            short8 B2 = *(const short8*)(bp + PB + base);
            short8 B3 = *(const short8*)(bp + 2 * PB + base);
            acc[t] = MFMA16(A1[ks], B1, acc[t]);
            acc[t] = MFMA16(A1[ks], B2, acc[t]);
            acc[t] = MFMA16(A2[ks], B1, acc[t]);
            acc[t] = MFMA16(A2[ks], B2, acc[t]);
            acc[t] = MFMA16(A1[ks], B3, acc[t]);
            acc[t] = MFMA16(A3[ks], B1, acc[t]);
        }
    }

    float inv_[16], bon_[16];
    #pragma unroll
    for (int t = 0; t < 16; ++t) {
        inv_[t] = invn_g[n0 + t * 16 + r_];
        bon_[t] = bonus_g[n0 + t * 16 + r_];
    }

    float m_[4], s_[4];
    #pragma unroll
    for (int r = 0; r < 4; ++r) {
        float m = -INFINITY;
        #pragma unroll
        for (int t = 0; t < 16; ++t)
            m = fmaxf(m, fmaf(acc[t][r], inv_[t], bon_[t]));
        #pragma unroll
        for (int d = 1; d <= 8; d <<= 1)
            m = fmaxf(m, __shfl_xor(m, d));
        float s = 0.f;
        #pragma unroll
        for (int t = 0; t < 16; ++t)
            s += __expf(fmaf(acc[t][r], inv_[t], bon_[t]) - m);
        #pragma unroll
        for (int d = 1; d <= 8; d <<= 1)
            s += __shfl_xor(s, d);
        m_[r] = m; s_[r] = s;
        if (r_ == 0) red[g_ * 4 + r][wave] = make_float2(m, s);
    }
    __syncthreads();

    const unsigned PTAB = 0xF5634F01u;
    const int pn = (PTAB >> (wave * 4)) & 0xF;
    float accw[16];
    #pragma unroll
    for (int t = 0; t < 16; ++t) accw[t] = 0.f;

    #pragma unroll
    for (int r = 0; r < 4; ++r) {
        const int row = g_ * 4 + r;
        float m = m_[r], s = s_[r];
        float M = m, Z = s;
        if (pn != 0xF) {
            float2 q = red[row][pn];
            M = fmaxf(m, q.x);
            Z = s * __expf(m - M) + q.y * __expf(q.x - M);
        }
        float coef = imp[rowBase + row] / Z * __expf(m - M);
        #pragma unroll
        for (int t = 0; t < 16; ++t)
            accw[t] = fmaf(coef, __expf(fmaf(acc[t][r], inv_[t], bon_[t]) - m), accw[t]);
    }

    #pragma unroll
    for (int t = 0; t < 16; ++t) {
        accw[t] += __shfl_xor(accw[t], 16);
        accw[t] += __shfl_xor(accw[t], 32);
    }
    #pragma unroll
    for (int tt = 0; tt < 4; ++tt) {
        int t = g_ * 4 + tt;
        float v = (tt == 0) ? accw[g_ * 4] : (tt == 1) ? accw[g_ * 4 + 1]
                : (tt == 2) ? accw[g_ * 4 + 2] : accw[g_ * 4 + 3];
        atomicAdd(&wout[b * 2048 + n0 + t * 16 + r_], v);
    }
}

// ---------------- top-k + softmax + sorted indices, one wave per (b,route) --
__global__ void topk_kernel(const float* __restrict__ w, float* __restrict__ out)
{
    const int lane = threadIdx.x;
    const int blk = blockIdx.x;          // 0..39
    const int b = blk / 5;
    const int route = blk % 5;

    const int segoff[5] = {0, 512, 768, 1280, 1792};
    const int seglen[5] = {512, 256, 512, 512, 256};
    const int kk[5]     = {64, 32, 64, 64, 32};
    const int soff[5]   = {0, 64, 96, 160, 224};
    const int ibase[5]  = {2048, 2560, 2816, 3328, 3840};

    const int L = seglen[route];
    const int K = kk[route];
    const int nv = L >> 6;               // 4 or 8 values per lane

    float v[8];
    #pragma unroll
    for (int i = 0; i < 8; ++i) {
        v[i] = -INFINITY;
        if (i < nv) v[i] = w[b * 2048 + segoff[route] + lane + 64 * i];
    }

    float selv = 0.f; int seli = 0;
    for (int it = 0; it < K; ++it) {
        float bv = -INFINITY; int bi = 0x7fffffff;
        #pragma unroll
        for (int i = 0; i < 8; ++i) {
            int li = lane + 64 * i;
            if (v[i] > bv || (v[i] == bv && li < bi)) { bv = v[i]; bi = li; }
        }
        for (int d = 1; d < 64; d <<= 1) {
            float ov = __shfl_xor(bv, d);
            int   oi = __shfl_xor(bi, d);
            if (ov > bv || (ov == bv && oi < bi)) { bv = ov; bi = oi; }
        }
        if (lane == it) { selv = bv; seli = bi; }
        #pragma unroll
        for (int i = 0; i < 8; ++i)
            if ((bi >> 6) == i && (bi & 63) == lane) v[i] = -INFINITY;
    }

    float m = __shfl(selv, 0);
    float e = (lane < K) ? __expf(selv - m) : 0.f;
    float s = e;
    for (int d = 1; d < 64; d <<= 1) s += __shfl_xor(s, d);
    if (lane < K) out[b * 256 + soff[route] + lane] = e / s;

    int rank = 0;
    for (int j = 0; j < K; ++j) {
        int oj = __shfl(seli, j);
        if (oj < seli) rank++;
    }
    if (lane < K) out[ibase[route] + b * K + rank] = (float)seli;
}

extern "C" void kernel_launch(void* const* d_in, const int* in_sizes, int n_in,
                              void* d_out, int out_size, void* d_ws, size_t ws_size,
                              hipStream_t stream)
{
    const float* x        = (const float*)d_in[0];
    const float* imp      = (const float*)d_in[1];
    const float* proj_w   = (const float*)d_in[2];
    const float* proj_b   = (const float*)d_in[3];
    const float* emb      = (const float*)d_in[4];
    const float* emb_rel  = (const float*)d_in[5];
    const float* ema_qk   = (const float*)d_in[6];
    const float* ema_v    = (const float*)d_in[7];
    const float* ema_rel  = (const float*)d_in[8];
    const float* ema_val  = (const float*)d_in[9];
    float* out = (float*)d_out;

    float* invn  = (float*)d_ws;                       // 2048 f32
    float* bonus = invn + 2048;                        // 2048 f32
    float* wacc  = bonus + 2048;                       // 16384 f32
    unsigned short* wp = (unsigned short*)(wacc + 16384);  // 3*PB u16
    unsigned short* bp = wp + 3 * PB;                  // 3*PB u16
    unsigned short* hs = bp + 3 * PB;                  // 3*PH u16 (6 MB)
    float* hpart = (float*)(hs + 3 * PH);              // 4*PH f32 (16 MB)

    prep_kernel<<<32, 64, 0, stream>>>(emb, emb_rel, ema_qk, ema_v, ema_rel, ema_val, invn, bonus, wacc);
    wtpack3_kernel<<<64, 256, 0, stream>>>(proj_w, wp);
    embpack_kernel<<<64, 256, 0, stream>>>(emb, emb_rel, bp);
    proj_kernel<<<dim3(256, 4), 256, 0, stream>>>(x, wp, hpart);
    hsumpack_kernel<<<512, 256, 0, stream>>>(hpart, proj_b, hs);
    route_kernel<<<1024, 512, 0, stream>>>(hs, bp, imp, invn, bonus, wacc);
    topk_kernel<<<40, 64, 0, stream>>>(wacc, out);
}

// Round 13
// 147.866 us; speedup vs baseline: 1.0365x; 1.0365x over previous
//
#include <hip/hip_runtime.h>
#include <cmath>

typedef __attribute__((ext_vector_type(8))) short short8;
typedef __attribute__((ext_vector_type(4))) float f32x4;

static __device__ __forceinline__ unsigned cvtpk(float lo, float hi) {
    unsigned r;
    asm("v_cvt_pk_bf16_f32 %0, %1, %2" : "=v"(r) : "v"(lo), "v"(hi));
    return r;
}
// 3-level RNE split of a pair of floats -> 3 packed-bf16 dwords; v = s1+s2+s3 + O(2^-27 |v|)
static __device__ __forceinline__ void split3pk(float v0, float v1,
                                                unsigned& o1, unsigned& o2, unsigned& o3) {
    o1 = cvtpk(v0, v1);
    float r0 = v0 - __uint_as_float(o1 << 16);
    float r1 = v1 - __uint_as_float(o1 & 0xffff0000u);
    o2 = cvtpk(r0, r1);
    float q0 = r0 - __uint_as_float(o2 << 16);
    float q1 = r1 - __uint_as_float(o2 & 0xffff0000u);
    o3 = cvtpk(q0, q1);
}

union FragU { short8 s; unsigned u[4]; };

// async 16B/lane global -> LDS DMA (dest = wave-uniform base + lane*16)
static __device__ __forceinline__ void gl_lds16(const void* g, void* l) {
    __builtin_amdgcn_global_load_lds(
        (const __attribute__((address_space(1))) unsigned*)g,
        (__attribute__((address_space(3))) unsigned*)l, 16, 0, 0);
}

#define PH 1048576   // h plane elems (16384*64)
#define PB 131072    // emb/W plane elems (2048*64)

// ---------------- setup: prep + wtpack + embpack in ONE launch ---------------
// blocks 0..63: W pack; 64..127: emb pack; 128..135: prep (invn/bonus/wacc)
__global__ void setup_kernel(const float* __restrict__ proj_w,
                             const float* __restrict__ emb,
                             const float* __restrict__ emb_rel_k,
                             const float* __restrict__ ema_qk,
                             const float* __restrict__ ema_v,
                             const float* __restrict__ ema_rel,
                             const float* __restrict__ ema_val,
                             unsigned short* __restrict__ wp,
                             unsigned short* __restrict__ bp,
                             float* __restrict__ invn,
                             float* __restrict__ bonus,
                             float* __restrict__ wacc)
{
    const int bid = blockIdx.x;
    const int tid = threadIdx.x;

    if (bid < 64) {
        // W pack: plane [ksg][t][lane][j]; col=16t+(l&15), k=ksg*32+(l>>4)*8+j
        int idx = bid * 256 + tid;              // 16384
        int l = idx & 63;
        int t = (idx >> 6) & 3;
        int ksg = idx >> 8;
        int col = t * 16 + (l & 15);
        int kb = ksg * 32 + (l >> 4) * 8;
        float4 w0 = *(const float4*)(proj_w + (size_t)col * 2048 + kb);
        float4 w1 = *(const float4*)(proj_w + (size_t)col * 2048 + kb + 4);
        float v[8] = {w0.x, w0.y, w0.z, w0.w, w1.x, w1.y, w1.z, w1.w};
        FragU s1, s2, s3;
        #pragma unroll
        for (int p = 0; p < 4; ++p)
            split3pk(v[2*p], v[2*p+1], s1.u[p], s2.u[p], s3.u[p]);
        size_t base = (size_t)ksg * 2048 + t * 512 + l * 8;
        *(short8*)(wp + base)          = s1.s;
        *(short8*)(wp + PB + base)     = s2.s;
        *(short8*)(wp + 2 * PB + base) = s3.s;
    } else if (bid < 128) {
        // emb pack: plane [nt][ks][lane][j]; neuron=nt*16+(l&15), k=ks*32+(l>>4)*8+j
        int idx = (bid - 64) * 256 + tid;       // 16384
        int l = idx & 63;
        int ks = (idx >> 6) & 1;
        int nt = idx >> 7;
        int n = nt * 16 + (l & 15);
        const float* src;
        if (n < 1280)      src = emb + (size_t)n * 64;
        else if (n < 1792) src = emb_rel_k + (size_t)(n - 1280) * 64;
        else               src = emb + (size_t)(n - 512) * 64;
        int c0 = ks * 32 + (l >> 4) * 8;
        float4 w0 = *(const float4*)(src + c0);
        float4 w1 = *(const float4*)(src + c0 + 4);
        float v[8] = {w0.x, w0.y, w0.z, w0.w, w1.x, w1.y, w1.z, w1.w};
        FragU s1, s2, s3;
        #pragma unroll
        for (int p = 0; p < 4; ++p)
            split3pk(v[2*p], v[2*p+1], s1.u[p], s2.u[p], s3.u[p]);
        size_t base = ((size_t)nt * 2 + ks) * 512 + l * 8;
        *(short8*)(bp + base)          = s1.s;
        *(short8*)(bp + PB + base)     = s2.s;
        *(short8*)(bp + 2 * PB + base) = s3.s;
    } else {
        // prep: invn/bonus per neuron + zero wacc
        int n = (bid - 128) * 256 + tid;        // 2048
        float4 z = {0.f, 0.f, 0.f, 0.f};
        *(float4*)(wacc + (size_t)n * 8)     = z;
        *(float4*)(wacc + (size_t)n * 8 + 4) = z;
        const float* row;
        float ema;
        if (n < 512)       { row = emb + (size_t)n * 64;                ema = ema_qk[n]; }
        else if (n < 768)  { row = emb + (size_t)n * 64;                ema = ema_v[n - 512]; }
        else if (n < 1280) { row = emb + (size_t)n * 64;                ema = ema_rel[n - 768]; }
        else if (n < 1792) { row = emb_rel_k + (size_t)(n - 1280) * 64; ema = ema_rel[n - 1280]; }
        else               { row = emb + (size_t)(n - 512) * 64;        ema = ema_val[n - 1792]; }
        float s = 0.f;
        #pragma unroll
        for (int k = 0; k < 64; k += 4) {
            float4 v = *(const float4*)(row + k);
            s += v.x*v.x + v.y*v.y + v.z*v.z + v.w*v.w;
        }
        invn[n] = 1.0f / sqrtf(s);
        float ex = 1.0f - ema * (1.0f / 1.5f);   // TAU = 1.5
        ex = fminf(fmaxf(ex, 0.f), 1.f);
        bonus[n] = ex * 1.0f;                    // EXC_W = 1.0
    }
}

#define MFMA16(a, b, c) __builtin_amdgcn_mfma_f32_16x16x32_bf16(a, b, c, 0, 0, 0)

// ---------------- proj GEMM v4: shared slab via global_load_lds DMA ---------
// grid (256 rowgroups, 4 kp); block = 4 waves, 64 rows, K-slice 512.
// Per k-step: each wave issues 3 async 1KB DMAs (its slice of the 12 KB slab)
// into the next buffer -- no staging VGPRs, no ds_writes; ONE barrier per step
// (compiler drains vmcnt before s_barrier). All 4 waves consume the same slab.
__launch_bounds__(256, 4)
__global__ void proj_kernel(const float* __restrict__ x,
                            const unsigned short* __restrict__ wp,
                            float* __restrict__ hpart)
{
    __shared__ short sBuf[2][6144];   // 2 x 12 KB: [plane 3][2048 shorts]

    const int tid = threadIdx.x;
    const int wave = tid >> 6, lane = tid & 63;
    const int g_ = lane >> 4, r_ = lane & 15;
    const int kp = blockIdx.y;
    const int row0 = blockIdx.x * 64 + wave * 16;

    const float* xa = x + (size_t)(row0 + r_) * 2048 + kp * 512 + g_ * 8;

    f32x4 acc[4];
    #pragma unroll
    for (int t = 0; t < 4; ++t) acc[t] = (f32x4){0.f, 0.f, 0.f, 0.f};

    // prologue: DMA slab for ksg0 into buf 0 (3 planes x 1 KB per wave)
    {
        const size_t srcb = (size_t)(kp * 16) * 2048 + wave * 512;
        #pragma unroll
        for (int p = 0; p < 3; ++p)
            gl_lds16(wp + (size_t)p * PB + srcb + lane * 8,
                     &sBuf[0][p * 2048 + wave * 512]);
    }
    __syncthreads();

    float4 a0 = *(const float4*)(xa);
    float4 a1 = *(const float4*)(xa + 4);
    int cur = 0;

    for (int ks = 0; ks < 16; ++ks) {
        // issue async DMA for next slab into the other buffer
        if (ks < 15) {
            const size_t srcb = (size_t)(kp * 16 + ks + 1) * 2048 + wave * 512;
            #pragma unroll
            for (int p = 0; p < 3; ++p)
                gl_lds16(wp + (size_t)p * PB + srcb + lane * 8,
                         &sBuf[cur ^ 1][p * 2048 + wave * 512]);
        }
        // A prefetch for next k-step
        float4 na0, na1;
        if (ks < 15) {
            na0 = *(const float4*)(xa + (ks + 1) * 32);
            na1 = *(const float4*)(xa + (ks + 1) * 32 + 4);
        }
        // B frags from the shared slab
        short8 B1[4], B2[4], B3[4];
        #pragma unroll
        for (int t = 0; t < 4; ++t) {
            B1[t] = *(const short8*)(&sBuf[cur][t * 512 + lane * 8]);
            B2[t] = *(const short8*)(&sBuf[cur][2048 + t * 512 + lane * 8]);
            B3[t] = *(const short8*)(&sBuf[cur][4096 + t * 512 + lane * 8]);
        }
        // split A (RNE x3 via cvt_pk)
        float av[8] = {a0.x, a0.y, a0.z, a0.w, a1.x, a1.y, a1.z, a1.w};
        FragU A1, A2, A3;
        #pragma unroll
        for (int p = 0; p < 4; ++p)
            split3pk(av[2*p], av[2*p+1], A1.u[p], A2.u[p], A3.u[p]);
        #pragma unroll
        for (int t = 0; t < 4; ++t) {
            acc[t] = MFMA16(A1.s, B1[t], acc[t]);
            acc[t] = MFMA16(A1.s, B2[t], acc[t]);
            acc[t] = MFMA16(A2.s, B1[t], acc[t]);
            acc[t] = MFMA16(A2.s, B2[t], acc[t]);
            acc[t] = MFMA16(A1.s, B3[t], acc[t]);
            acc[t] = MFMA16(A3.s, B1[t], acc[t]);
        }
        if (ks < 15) {
            __syncthreads();    // drains DMA (vmcnt) + flips buffer
            cur ^= 1;
        }
        a0 = na0; a1 = na1;
    }

    // coalesced partial store: row = g_*4+rr, col = t*16+r_
    float* hp = hpart + (size_t)kp * PH + (size_t)row0 * 64;
    #pragma unroll
    for (int t = 0; t < 4; ++t)
        #pragma unroll
        for (int rr = 0; rr < 4; ++rr)
            hp[(g_ * 4 + rr) * 64 + t * 16 + r_] = acc[t][rr];
}

// ---------------- hsum + pack: h = sum 4 partials + bias -> 3 A-frag planes -
__global__ void hsumpack_kernel(const float* __restrict__ hpart,
                                const float* __restrict__ proj_b,
                                unsigned short* __restrict__ hs)
{
    int idx = blockIdx.x * 256 + threadIdx.x;   // 131072
    int lane = idx & 63;
    int ks = (idx >> 6) & 1;
    int rg = idx >> 7;
    int row = rg * 16 + (lane & 15);
    int c0 = ks * 32 + (lane >> 4) * 8;
    size_t o = (size_t)row * 64 + c0;

    float4 s0 = *(const float4*)(hpart + o);
    float4 s1 = *(const float4*)(hpart + o + 4);
    #pragma unroll
    for (int p = 1; p < 4; ++p) {
        float4 u0 = *(const float4*)(hpart + (size_t)p * PH + o);
        float4 u1 = *(const float4*)(hpart + (size_t)p * PH + o + 4);
        s0.x += u0.x; s0.y += u0.y; s0.z += u0.z; s0.w += u0.w;
        s1.x += u1.x; s1.y += u1.y; s1.z += u1.z; s1.w += u1.w;
    }
    float4 b0 = *(const float4*)(proj_b + c0);
    float4 b1 = *(const float4*)(proj_b + c0 + 4);
    s0.x += b0.x; s0.y += b0.y; s0.z += b0.z; s0.w += b0.w;
    s1.x += b1.x; s1.y += b1.y; s1.z += b1.z; s1.w += b1.w;

    float hv[8] = {s0.x, s0.y, s0.z, s0.w, s1.x, s1.y, s1.z, s1.w};
    FragU t1, t2, t3;
    #pragma unroll
    for (int p = 0; p < 4; ++p)
        split3pk(hv[2*p], hv[2*p+1], t1.u[p], t2.u[p], t3.u[p]);
    size_t base = ((size_t)rg * 2 + ks) * 512 + lane * 8;
    *(short8*)(hs + base)          = t1.s;
    *(short8*)(hs + PH + base)     = t2.s;
    *(short8*)(hs + 2 * PH + base) = t3.s;
}

// ---------------- routing via MFMA (round-8 form: best measured) ------------
// Block: 16 rows, 8 waves (512 thr); wave w owns neurons [w*256, w*256+256).
// Segments align to waves: 0-1=qk, 2=fv, 3-4=q, 5-6=k, 7=val.
__launch_bounds__(512, 4)
__global__ void route_kernel(const unsigned short* __restrict__ hs,
                             const unsigned short* __restrict__ bp,
                             const float* __restrict__ imp,
                             const float* __restrict__ invn_g,
                             const float* __restrict__ bonus_g,
                             float* __restrict__ wout)
{
    __shared__ float2 red[16][8];

    const int tid = threadIdx.x;
    const int wave = tid >> 6, lane = tid & 63;
    const int g_ = lane >> 4, r_ = lane & 15;
    const int rowBase = blockIdx.x * 16;
    const int b = rowBase >> 11;
    const int n0 = wave * 256;

    short8 A1[2], A2[2], A3[2];
    #pragma unroll
    for (int ks = 0; ks < 2; ++ks) {
        size_t base = ((size_t)blockIdx.x * 2 + ks) * 512 + lane * 8;
        A1[ks] = *(const short8*)(hs + base);
        A2[ks] = *(const short8*)(hs + PH + base);
        A3[ks] = *(const short8*)(hs + 2 * PH + base);
    }

    f32x4 acc[16];
    #pragma unroll
    for (int t = 0; t < 16; ++t) acc[t] = (f32x4){0.f, 0.f, 0.f, 0.f};

    #pragma unroll
    for (int t = 0; t < 16; ++t) {
        const int nt = wave * 16 + t;
        #pragma unroll
        for (int ks = 0; ks < 2; ++ks) {
            size_t base = ((size_t)nt * 2 + ks) * 512 + lane * 8;
            short8 B1 = *(const short8*)(bp + base);
            short8 B2 = *(const short8*)(bp + PB + base);
            short8 B3 = *(const short8*)(bp + 2 * PB + base);
            acc[t] = MFMA16(A1[ks], B1, acc[t]);
            acc[t] = MFMA16(A1[ks], B2, acc[t]);
            acc[t] = MFMA16(A2[ks], B1, acc[t]);
            acc[t] = MFMA16(A2[ks], B2, acc[t]);
            acc[t] = MFMA16(A1[ks], B3, acc[t]);
            acc[t] = MFMA16(A3[ks], B1, acc[t]);
        }
    }

    float inv_[16], bon_[16];
    #pragma unroll
    for (int t = 0; t < 16; ++t) {
        inv_[t] = invn_g[n0 + t * 16 + r_];
        bon_[t] = bonus_g[n0 + t * 16 + r_];
    }

    float m_[4], s_[4];
    #pragma unroll
    for (int r = 0; r < 4; ++r) {
        float m = -INFINITY;
        #pragma unroll
        for (int t = 0; t < 16; ++t)
            m = fmaxf(m, fmaf(acc[t][r], inv_[t], bon_[t]));
        #pragma unroll
        for (int d = 1; d <= 8; d <<= 1)
            m = fmaxf(m, __shfl_xor(m, d));
        float s = 0.f;
        #pragma unroll
        for (int t = 0; t < 16; ++t)
            s += __expf(fmaf(acc[t][r], inv_[t], bon_[t]) - m);
        #pragma unroll
        for (int d = 1; d <= 8; d <<= 1)
            s += __shfl_xor(s, d);
        m_[r] = m; s_[r] = s;
        if (r_ == 0) red[g_ * 4 + r][wave] = make_float2(m, s);
    }
    __syncthreads();

    const unsigned PTAB = 0xF5634F01u;
    const int pn = (PTAB >> (wave * 4)) & 0xF;
    float accw[16];
    #pragma unroll
    for (int t = 0; t < 16; ++t) accw[t] = 0.f;

    #pragma unroll
    for (int r = 0; r < 4; ++r) {
        const int row = g_ * 4 + r;
        float m = m_[r], s = s_[r];
        float M = m, Z = s;
        if (pn != 0xF) {
            float2 q = red[row][pn];
            M = fmaxf(m, q.x);
            Z = s * __expf(m - M) + q.y * __expf(q.x - M);
        }
        float coef = imp[rowBase + row] / Z * __expf(m - M);
        #pragma unroll
        for (int t = 0; t < 16; ++t)
            accw[t] = fmaf(coef, __expf(fmaf(acc[t][r], inv_[t], bon_[t]) - m), accw[t]);
    }

    #pragma unroll
    for (int t = 0; t < 16; ++t) {
        accw[t] += __shfl_xor(accw[t], 16);
        accw[t] += __shfl_xor(accw[t], 32);
    }
    #pragma unroll
    for (int tt = 0; tt < 4; ++tt) {
        int t = g_ * 4 + tt;
        float v = (tt == 0) ? accw[g_ * 4] : (tt == 1) ? accw[g_ * 4 + 1]
                : (tt == 2) ? accw[g_ * 4 + 2] : accw[g_ * 4 + 3];
        atomicAdd(&wout[b * 2048 + n0 + t * 16 + r_], v);
    }
}

// ---------------- top-k + softmax + sorted indices, one wave per (b,route) --
__global__ void topk_kernel(const float* __restrict__ w, float* __restrict__ out)
{
    const int lane = threadIdx.x;
    const int blk = blockIdx.x;          // 0..39
    const int b = blk / 5;
    const int route = blk % 5;

    const int segoff[5] = {0, 512, 768, 1280, 1792};
    const int seglen[5] = {512, 256, 512, 512, 256};
    const int kk[5]     = {64, 32, 64, 64, 32};
    const int soff[5]   = {0, 64, 96, 160, 224};
    const int ibase[5]  = {2048, 2560, 2816, 3328, 3840};

    const int L = seglen[route];
    const int K = kk[route];
    const int nv = L >> 6;               // 4 or 8 values per lane

    float v[8];
    #pragma unroll
    for (int i = 0; i < 8; ++i) {
        v[i] = -INFINITY;
        if (i < nv) v[i] = w[b * 2048 + segoff[route] + lane + 64 * i];
    }

    float selv = 0.f; int seli = 0;
    for (int it = 0; it < K; ++it) {
        float bv = -INFINITY; int bi = 0x7fffffff;
        #pragma unroll
        for (int i = 0; i < 8; ++i) {
            int li = lane + 64 * i;
            if (v[i] > bv || (v[i] == bv && li < bi)) { bv = v[i]; bi = li; }
        }
        for (int d = 1; d < 64; d <<= 1) {
            float ov = __shfl_xor(bv, d);
            int   oi = __shfl_xor(bi, d);
            if (ov > bv || (ov == bv && oi < bi)) { bv = ov; bi = oi; }
        }
        if (lane == it) { selv = bv; seli = bi; }
        #pragma unroll
        for (int i = 0; i < 8; ++i)
            if ((bi >> 6) == i && (bi & 63) == lane) v[i] = -INFINITY;
    }

    float m = __shfl(selv, 0);
    float e = (lane < K) ? __expf(selv - m) : 0.f;
    float s = e;
    for (int d = 1; d < 64; d <<= 1) s += __shfl_xor(s, d);
    if (lane < K) out[b * 256 + soff[route] + lane] = e / s;

    int rank = 0;
    for (int j = 0; j < K; ++j) {
        int oj = __shfl(seli, j);
        if (oj < seli) rank++;
    }
    if (lane < K) out[ibase[route] + b * K + rank] = (float)seli;
}

extern "C" void kernel_launch(void* const* d_in, const int* in_sizes, int n_in,
                              void* d_out, int out_size, void* d_ws, size_t ws_size,
                              hipStream_t stream)
{
    const float* x        = (const float*)d_in[0];
    const float* imp      = (const float*)d_in[1];
    const float* proj_w   = (const float*)d_in[2];
    const float* proj_b   = (const float*)d_in[3];
    const float* emb      = (const float*)d_in[4];
    const float* emb_rel  = (const float*)d_in[5];
    const float* ema_qk   = (const float*)d_in[6];
    const float* ema_v    = (const float*)d_in[7];
    const float* ema_rel  = (const float*)d_in[8];
    const float* ema_val  = (const float*)d_in[9];
    float* out = (float*)d_out;

    float* invn  = (float*)d_ws;                       // 2048 f32
    float* bonus = invn + 2048;                        // 2048 f32
    float* wacc  = bonus + 2048;                       // 16384 f32
    unsigned short* wp = (unsigned short*)(wacc + 16384);  // 3*PB u16
    unsigned short* bp = wp + 3 * PB;                  // 3*PB u16
    unsigned short* hs = bp + 3 * PB;                  // 3*PH u16 (6 MB)
    float* hpart = (float*)(hs + 3 * PH);              // 4*PH f32 (16 MB)

    setup_kernel<<<136, 256, 0, stream>>>(proj_w, emb, emb_rel, ema_qk, ema_v,
                                          ema_rel, ema_val, wp, bp, invn, bonus, wacc);
    proj_kernel<<<dim3(256, 4), 256, 0, stream>>>(x, wp, hpart);
    hsumpack_kernel<<<512, 256, 0, stream>>>(hpart, proj_b, hs);
    route_kernel<<<1024, 512, 0, stream>>>(hs, bp, imp, invn, bonus, wacc);
    topk_kernel<<<40, 64, 0, stream>>>(wacc, out);
}